// Round 1
// baseline (1300.530 us; speedup 1.0000x reference)
//
#include <hip/hip_runtime.h>
#include <cmath>

// Weighted log-softmax NLL:
//   out = -(1/B) * sum_b (2*a1_freq[b])^gramma * ( x[b,y0[b]] - logsumexp(x[b,:]) )
// One block per row, online (streaming) logsumexp, float4 loads.

__global__ __launch_bounds__(256) void ce_loss_kernel(
    const float* __restrict__ x,
    const int*   __restrict__ y0,
    const float* __restrict__ a1,
    const int*   __restrict__ gramma,
    float*       __restrict__ out,
    int B, int C)
{
    const int row = blockIdx.x;
    const float* xrow = x + (size_t)row * (size_t)C;

    float m = -INFINITY;
    float s = 0.0f;

    auto upd = [&](float v) {
        if (v > m) {
            // rescale old sum to new max; exp(-inf) = 0 handles first element
            s = s * __expf(m - v) + 1.0f;
            m = v;
        } else {
            s += __expf(v - m);
        }
    };

    // vectorized main body (C % 4 == 0 for this problem; tail loop kept for safety)
    const int n4 = C >> 2;
    const float4* xr4 = reinterpret_cast<const float4*>(xrow);
    for (int i = threadIdx.x; i < n4; i += blockDim.x) {
        float4 v = xr4[i];
        upd(v.x); upd(v.y); upd(v.z); upd(v.w);
    }
    for (int i = (n4 << 2) + threadIdx.x; i < C; i += blockDim.x) {
        upd(xrow[i]);
    }

    // wave-64 reduction of (m, s)
    #pragma unroll
    for (int off = 32; off >= 1; off >>= 1) {
        float mo = __shfl_down(m, off, 64);
        float so = __shfl_down(s, off, 64);
        float nm = fmaxf(m, mo);
        s = s * __expf(m - nm) + so * __expf(mo - nm);
        m = nm;
    }

    // cross-wave reduction via LDS (256 threads = 4 waves)
    __shared__ float sm[4];
    __shared__ float ss[4];
    const int lane = threadIdx.x & 63;
    const int wid  = threadIdx.x >> 6;
    if (lane == 0) { sm[wid] = m; ss[wid] = s; }
    __syncthreads();

    if (threadIdx.x == 0) {
        float M = sm[0];
        float S = ss[0];
        #pragma unroll
        for (int w = 1; w < 4; ++w) {
            float mo = sm[w], so = ss[w];
            float nm = fmaxf(M, mo);
            S = S * __expf(M - nm) + so * __expf(mo - nm);
            M = nm;
        }
        const float lse = M + logf(S);
        const int   idx = y0[row];
        const float xy  = xrow[idx];
        const float a   = a1[row];
        const int   g   = gramma[0];
        const float w   = (g == 1) ? (2.0f * a) : powf(2.0f * a, (float)g);
        const float contrib = -w * (xy - lse) / (float)B;
        atomicAdd(out, contrib);
    }
}

extern "C" void kernel_launch(void* const* d_in, const int* in_sizes, int n_in,
                              void* d_out, int out_size, void* d_ws, size_t ws_size,
                              hipStream_t stream) {
    const float* x      = (const float*)d_in[0];
    const int*   y0     = (const int*)d_in[1];
    const float* a1     = (const float*)d_in[2];
    const int*   gramma = (const int*)d_in[3];
    float*       out    = (float*)d_out;

    const int B = in_sizes[1];          // 8192
    const int C = in_sizes[0] / B;      // 32000

    // d_out is poisoned to 0xAA before every timed replay; zero it (capture-safe).
    hipMemsetAsync(out, 0, sizeof(float), stream);
    ce_loss_kernel<<<B, 256, 0, stream>>>(x, y0, a1, gramma, out, B, C);
}